// Round 1
// baseline (13983.049 us; speedup 1.0000x reference)
//
#include <hip/hip_runtime.h>
#include <math.h>

namespace {

constexpr int kB = 4, kN = 512, kC = 256, kH = 8, kD = 32, kDG = 6, kHID = 16;

__device__ __forceinline__ float swishf(float x) {
    // x * sigmoid(x); v_rcp/v_exp precision ~1ulp, fine vs 6.4e-3 threshold
    return x * __builtin_amdgcn_rcpf(1.0f + __expf(-x));
}

// Mask arrives as either 1-byte bool or 4-byte int (harness ambiguity).
// Detect: random bool data has nonzero bytes at offsets %4 != 0 with
// probability 1 - 2^-1536; int32 0/1 values never do. Write clean ints.
__global__ void k_decode_mask(const unsigned char* __restrict__ raw,
                              int* __restrict__ out, int n) {
    __shared__ int s_isbool;
    if (threadIdx.x == 0) s_isbool = 0;
    __syncthreads();
    int found = 0;
    for (int i = threadIdx.x; i < n; i += blockDim.x)
        if ((i & 3) && raw[i]) found = 1;
    if (found) atomicOr(&s_isbool, 1);
    __syncthreads();
    const int isb = s_isbool;
    const int* ri = (const int*)raw;
    for (int i = threadIdx.x; i < n; i += blockDim.x)
        out[i] = isb ? (int)(raw[i] != 0) : (int)(ri[i] != 0);
}

// Q/K/V projection: 8 rows per block, col t per thread.
__global__ __launch_bounds__(256) void k_qkv(
    const float* __restrict__ x,
    const float* __restrict__ wq, const float* __restrict__ bq,
    const float* __restrict__ wk, const float* __restrict__ bk,
    const float* __restrict__ wv, const float* __restrict__ bv,
    float* __restrict__ Q, float* __restrict__ K, float* __restrict__ V) {
    __shared__ float sx[8][kC];
    const int r0 = blockIdx.x * 8;
    const int t = threadIdx.x;
    #pragma unroll
    for (int r = 0; r < 8; ++r) sx[r][t] = x[(r0 + r) * kC + t];
    __syncthreads();
    float aq[8] = {}, ak[8] = {}, av[8] = {};
    for (int k = 0; k < kC; ++k) {
        const float q = wq[k * kC + t];   // coalesced
        const float kk = wk[k * kC + t];
        const float v = wv[k * kC + t];
        #pragma unroll
        for (int r = 0; r < 8; ++r) {     // sx broadcast reads: free
            aq[r] += sx[r][k] * q;
            ak[r] += sx[r][k] * kk;
            av[r] += sx[r][k] * v;
        }
    }
    const float qb = bq[t], kb = bk[t], vb = bv[t];
    #pragma unroll
    for (int r = 0; r < 8; ++r) {
        Q[(r0 + r) * kC + t] = aq[r] + qb;
        K[(r0 + r) * kC + t] = ak[r] + kb;
        V[(r0 + r) * kC + t] = av[r] + vb;
    }
}

// Fused: pairwise MLP + QK^T + mask + softmax + att@V. One block per (b,n).
__global__ __launch_bounds__(256) void k_attn(
    const float* __restrict__ G,
    const float* __restrict__ Q,
    const float* __restrict__ K,
    const float* __restrict__ V,
    const float* __restrict__ w1, const float* __restrict__ b1,
    const float* __restrict__ w2, const float* __restrict__ b2,
    const float* __restrict__ w3, const float* __restrict__ b3,
    const int* __restrict__ mask,
    float* __restrict__ out) {
    __shared__ float sQ[kC];                 // 1 KB
    __shared__ float sG[kN * kDG];           // 12 KB
    __shared__ float sW1[kH][kDG][kHID];     // 3 KB
    __shared__ float sB1[kH][kHID];
    __shared__ float sW2[kH][kHID][kHID];    // 8 KB
    __shared__ float sB2[kH][kHID];
    __shared__ float sW3[kH][kHID];
    __shared__ float sB3[kH];
    __shared__ float sAtt[kH][kN];           // 16 KB, [h][m]: conflict-free
    __shared__ float sInv[kH];

    const int bn = blockIdx.x;    // 0..2047
    const int b = bn >> 9;
    const int t = threadIdx.x;

    sQ[t] = Q[bn * kC + t];
    {
        const float4* gsrc = (const float4*)(G + (size_t)bn * (kN * kDG));
        float4* gdst = (float4*)sG;
        #pragma unroll
        for (int i = 0; i < 3; ++i) gdst[t + 256 * i] = gsrc[t + 256 * i];
    }
    for (int i = t; i < kH * kDG * kHID; i += 256) (&sW1[0][0][0])[i] = w1[i];
    for (int i = t; i < kH * kHID; i += 256) (&sB1[0][0])[i] = b1[i];
    for (int i = t; i < kH * kHID * kHID; i += 256) (&sW2[0][0][0])[i] = w2[i];
    for (int i = t; i < kH * kHID; i += 256) (&sB2[0][0])[i] = b2[i];
    for (int i = t; i < kH * kHID; i += 256) (&sW3[0][0])[i] = w3[i];
    if (t < kH) sB3[t] = b3[t];
    __syncthreads();

    const float* Kb = K + (size_t)b * kN * kC;
    #pragma unroll
    for (int half = 0; half < 2; ++half) {
        const int m = t + half * 256;
        const float* gm = &sG[m * kDG];
        const float g0 = gm[0], g1 = gm[1], g2 = gm[2];
        const float g3 = gm[3], g4 = gm[4], g5 = gm[5];
        const float4* kr = (const float4*)(Kb + (size_t)m * kC);
        const int valid = mask[b * kN + m];
        #pragma unroll
        for (int h = 0; h < kH; ++h) {
            float x1[kHID];
            #pragma unroll
            for (int k = 0; k < kHID; ++k) {
                float a = sB1[h][k];      // all weight reads wave-uniform
                a += g0 * sW1[h][0][k];
                a += g1 * sW1[h][1][k];
                a += g2 * sW1[h][2][k];
                a += g3 * sW1[h][3][k];
                a += g4 * sW1[h][4][k];
                a += g5 * sW1[h][5][k];
                x1[k] = swishf(a);
            }
            float x2[kHID];
            #pragma unroll
            for (int j = 0; j < kHID; ++j) {
                float a = sB2[h][j];
                #pragma unroll
                for (int k = 0; k < kHID; ++k) a += x1[k] * sW2[h][k][j];
                x2[j] = swishf(a);
            }
            float a3 = sB3[h];
            #pragma unroll
            for (int j = 0; j < kHID; ++j) a3 += x2[j] * sW3[h][j];
            const float aloc = swishf(a3);
            // A_feat: Q[n,h,:] . K[m,h,:] / 16
            float af = 0.f;
            #pragma unroll
            for (int q4 = 0; q4 < kD / 4; ++q4) {
                const float4 kv = kr[h * (kD / 4) + q4];
                const float* qp = &sQ[h * kD + q4 * 4];
                af += kv.x * qp[0];
                af += kv.y * qp[1];
                af += kv.z * qp[2];
                af += kv.w * qp[3];
            }
            const float pre = aloc + af * 0.0625f;
            sAtt[h][m] = valid ? pre : -1e38f;
        }
    }
    __syncthreads();

    // Per-head softmax over m: 32-lane group per head; shuffle masks <32
    // never cross the wave's 32-lane halves.
    {
        const int hg = t >> 5;
        const int lane = t & 31;
        float mx = -3.4e38f;
        #pragma unroll
        for (int j = 0; j < kN / 32; ++j)
            mx = fmaxf(mx, sAtt[hg][lane + 32 * j]);
        #pragma unroll
        for (int off = 16; off; off >>= 1)
            mx = fmaxf(mx, __shfl_xor(mx, off));
        float lsum = 0.f;
        #pragma unroll
        for (int j = 0; j < kN / 32; ++j) {
            const int idx = lane + 32 * j;
            const float e = __expf(sAtt[hg][idx] - mx);  // all-masked row: exp(0)=1 -> uniform, matches ref
            sAtt[hg][idx] = e;
            lsum += e;
        }
        #pragma unroll
        for (int off = 16; off; off >>= 1)
            lsum += __shfl_xor(lsum, off);
        if (lane == 0) sInv[hg] = 1.0f / lsum;
    }
    __syncthreads();

    // att @ V: thread (h, d); V reads coalesced (two 128B segs per wave).
    {
        const int h = t >> 5;
        const int dd = t & 31;
        const float* vp = V + (size_t)b * kN * kC + h * kD + dd;
        float a0 = 0.f, a1 = 0.f, a2 = 0.f, a3 = 0.f;
        for (int m = 0; m < kN; m += 4) {
            a0 += sAtt[h][m + 0] * vp[(size_t)(m + 0) * kC];
            a1 += sAtt[h][m + 1] * vp[(size_t)(m + 1) * kC];
            a2 += sAtt[h][m + 2] * vp[(size_t)(m + 2) * kC];
            a3 += sAtt[h][m + 3] * vp[(size_t)(m + 3) * kC];
        }
        out[bn * kC + t] = ((a0 + a1) + (a2 + a3)) * sInv[h];
    }
}

// Final projection: out_pre @ out_w + out_b
__global__ __launch_bounds__(256) void k_proj(
    const float* __restrict__ x,
    const float* __restrict__ w, const float* __restrict__ bias,
    float* __restrict__ y) {
    __shared__ float sx[8][kC];
    const int r0 = blockIdx.x * 8;
    const int t = threadIdx.x;
    #pragma unroll
    for (int r = 0; r < 8; ++r) sx[r][t] = x[(r0 + r) * kC + t];
    __syncthreads();
    float acc[8] = {};
    for (int k = 0; k < kC; ++k) {
        const float wv = w[k * kC + t];
        #pragma unroll
        for (int r = 0; r < 8; ++r) acc[r] += sx[r][k] * wv;
    }
    const float bb = bias[t];
    #pragma unroll
    for (int r = 0; r < 8; ++r) y[(r0 + r) * kC + t] = acc[r] + bb;
}

}  // namespace

extern "C" void kernel_launch(void* const* d_in, const int* in_sizes, int n_in,
                              void* d_out, int out_size, void* d_ws, size_t ws_size,
                              hipStream_t stream) {
    (void)in_sizes; (void)n_in; (void)out_size; (void)ws_size;
    const float* G  = (const float*)d_in[0];
    const float* cf = (const float*)d_in[1];
    const float* wq = (const float*)d_in[2];
    const float* bq = (const float*)d_in[3];
    const float* wk = (const float*)d_in[4];
    const float* bk = (const float*)d_in[5];
    const float* wv = (const float*)d_in[6];   // in_w
    const float* bv = (const float*)d_in[7];   // in_b
    const float* wo = (const float*)d_in[8];   // out_w
    const float* bo = (const float*)d_in[9];   // out_b
    const float* w1 = (const float*)d_in[10];
    const float* b1 = (const float*)d_in[11];
    const float* w2 = (const float*)d_in[12];
    const float* b2 = (const float*)d_in[13];
    const float* w3 = (const float*)d_in[14];
    const float* b3 = (const float*)d_in[15];
    const unsigned char* mraw = (const unsigned char*)d_in[16];

    const int rows = kB * kN;  // 2048
    float* Q = (float*)d_ws;
    float* K = Q + (size_t)rows * kC;
    float* V = K + (size_t)rows * kC;
    float* O = V + (size_t)rows * kC;
    int* mi  = (int*)(O + (size_t)rows * kC);
    // ws usage: 4 * 2 MB + 8 KB

    k_decode_mask<<<1, 256, 0, stream>>>(mraw, mi, rows);
    k_qkv<<<rows / 8, 256, 0, stream>>>(cf, wq, bq, wk, bk, wv, bv, Q, K, V);
    k_attn<<<rows, 256, 0, stream>>>(G, Q, K, V, w1, b1, w2, b2, w3, b3, mi, O);
    k_proj<<<rows / 8, 256, 0, stream>>>(O, wo, bo, (float*)d_out);
}

// Round 2
// 372.280 us; speedup vs baseline: 37.5605x; 37.5605x over previous
//
#include <hip/hip_runtime.h>
#include <math.h>

namespace {

constexpr int kB = 4, kN = 512, kC = 256, kH = 8, kD = 32, kDG = 6, kHID = 16;

__device__ __forceinline__ float swishf(float x) {
    // x * sigmoid(x); v_rcp/v_exp precision ~1ulp, fine vs 6.4e-3 threshold
    return x * __builtin_amdgcn_rcpf(1.0f + __expf(-x));
}

// Mask arrives as either 1-byte bool or 4-byte int (harness ambiguity).
// Detect: random bool data has nonzero bytes at offsets %4 != 0 with
// probability 1 - 2^-1536; int32 0/1 values never do. Write clean ints.
__global__ void k_decode_mask(const unsigned char* __restrict__ raw,
                              int* __restrict__ out, int n) {
    __shared__ int s_isbool;
    if (threadIdx.x == 0) s_isbool = 0;
    __syncthreads();
    int found = 0;
    for (int i = threadIdx.x; i < n; i += blockDim.x)
        if ((i & 3) && raw[i]) found = 1;
    if (found) atomicOr(&s_isbool, 1);
    __syncthreads();
    const int isb = s_isbool;
    const int* ri = (const int*)raw;
    for (int i = threadIdx.x; i < n; i += blockDim.x)
        out[i] = isb ? (int)(raw[i] != 0) : (int)(ri[i] != 0);
}

// Q/K/V projection: 8 rows per block, col t per thread.
__global__ __launch_bounds__(256) void k_qkv(
    const float* __restrict__ x,
    const float* __restrict__ wq, const float* __restrict__ bq,
    const float* __restrict__ wk, const float* __restrict__ bk,
    const float* __restrict__ wv, const float* __restrict__ bv,
    float* __restrict__ Q, float* __restrict__ K, float* __restrict__ V) {
    __shared__ float sx[8][kC];
    const int r0 = blockIdx.x * 8;
    const int t = threadIdx.x;
    #pragma unroll
    for (int r = 0; r < 8; ++r) sx[r][t] = x[(r0 + r) * kC + t];
    __syncthreads();
    float aq[8] = {}, ak[8] = {}, av[8] = {};
    for (int k = 0; k < kC; ++k) {
        const float q = wq[k * kC + t];   // coalesced
        const float kk = wk[k * kC + t];
        const float v = wv[k * kC + t];
        #pragma unroll
        for (int r = 0; r < 8; ++r) {     // sx broadcast reads: free
            aq[r] += sx[r][k] * q;
            ak[r] += sx[r][k] * kk;
            av[r] += sx[r][k] * v;
        }
    }
    const float qb = bq[t], kb = bk[t], vb = bv[t];
    #pragma unroll
    for (int r = 0; r < 8; ++r) {
        Q[(r0 + r) * kC + t] = aq[r] + qb;
        K[(r0 + r) * kC + t] = ak[r] + kb;
        V[(r0 + r) * kC + t] = av[r] + vb;
    }
}

// Fused: pairwise MLP + QK^T + mask + softmax + att@V. One block per (b,n).
// Register discipline: h-loop NOT unrolled (one head's MLP state live at a
// time, both m's processed inside so each uniform LDS weight read feeds 2
// evals); __launch_bounds__(256,2) caps at 128 VGPRs (round-1 version hit
// 256 VGPR + 13.6 GB spill traffic).
__global__ __launch_bounds__(256, 2) void k_attn(
    const float* __restrict__ G,
    const float* __restrict__ Q,
    const float* __restrict__ K,
    const float* __restrict__ V,
    const float* __restrict__ w1, const float* __restrict__ b1,
    const float* __restrict__ w2, const float* __restrict__ b2,
    const float* __restrict__ w3, const float* __restrict__ b3,
    const int* __restrict__ mask,
    float* __restrict__ out) {
    __shared__ float sQ[kC];                 // 1 KB
    __shared__ float sG[kN * kDG];           // 12 KB
    __shared__ float sW1[kH][kDG][kHID];     // 3 KB
    __shared__ float sB1[kH][kHID];
    __shared__ float sW2[kH][kHID][kHID];    // 8 KB
    __shared__ float sB2[kH][kHID];
    __shared__ float sW3[kH][kHID];
    __shared__ float sB3[kH];
    __shared__ float sAtt[kH][kN];           // 16 KB, [h][m]: conflict-free
    __shared__ float sInv[kH];

    const int bn = blockIdx.x;    // 0..2047
    const int b = bn >> 9;
    const int t = threadIdx.x;

    sQ[t] = Q[bn * kC + t];
    {
        const float4* gsrc = (const float4*)(G + (size_t)bn * (kN * kDG));
        float4* gdst = (float4*)sG;
        #pragma unroll
        for (int i = 0; i < 3; ++i) gdst[t + 256 * i] = gsrc[t + 256 * i];
    }
    for (int i = t; i < kH * kDG * kHID; i += 256) (&sW1[0][0][0])[i] = w1[i];
    for (int i = t; i < kH * kHID; i += 256) (&sB1[0][0])[i] = b1[i];
    for (int i = t; i < kH * kHID * kHID; i += 256) (&sW2[0][0][0])[i] = w2[i];
    for (int i = t; i < kH * kHID; i += 256) (&sB2[0][0])[i] = b2[i];
    for (int i = t; i < kH * kHID; i += 256) (&sW3[0][0])[i] = w3[i];
    if (t < kH) sB3[t] = b3[t];
    __syncthreads();

    {
        const float* Kb = K + (size_t)b * kN * kC;
        const int mA = t, mB = t + 256;
        const float* gA = &sG[mA * kDG];
        const float* gB = &sG[mB * kDG];
        const float ga0 = gA[0], ga1 = gA[1], ga2 = gA[2];
        const float ga3 = gA[3], ga4 = gA[4], ga5 = gA[5];
        const float gb0 = gB[0], gb1 = gB[1], gb2 = gB[2];
        const float gb3 = gB[3], gb4 = gB[4], gb5 = gB[5];
        const int vA = mask[b * kN + mA];
        const int vB = mask[b * kN + mB];
        const float4* krA = (const float4*)(Kb + (size_t)mA * kC);
        const float4* krB = (const float4*)(Kb + (size_t)mB * kC);

        #pragma unroll 1
        for (int h = 0; h < kH; ++h) {
            // ---- layer 1: [6] -> [16], both m's share the weight reads ----
            float xA[kHID], xB[kHID];
            #pragma unroll
            for (int k4 = 0; k4 < 4; ++k4) {
                const float4 bv = ((const float4*)&sB1[h][0])[k4];
                float4 aA = bv, aB = bv;
                #pragma unroll
                for (int g = 0; g < kDG; ++g) {
                    const float4 w = ((const float4*)&sW1[h][g][0])[k4];
                    const float gva = (g == 0) ? ga0 : (g == 1) ? ga1 : (g == 2) ? ga2
                                     : (g == 3) ? ga3 : (g == 4) ? ga4 : ga5;
                    const float gvb = (g == 0) ? gb0 : (g == 1) ? gb1 : (g == 2) ? gb2
                                     : (g == 3) ? gb3 : (g == 4) ? gb4 : gb5;
                    aA.x += gva * w.x; aA.y += gva * w.y; aA.z += gva * w.z; aA.w += gva * w.w;
                    aB.x += gvb * w.x; aB.y += gvb * w.y; aB.z += gvb * w.z; aB.w += gvb * w.w;
                }
                xA[k4 * 4 + 0] = swishf(aA.x); xA[k4 * 4 + 1] = swishf(aA.y);
                xA[k4 * 4 + 2] = swishf(aA.z); xA[k4 * 4 + 3] = swishf(aA.w);
                xB[k4 * 4 + 0] = swishf(aB.x); xB[k4 * 4 + 1] = swishf(aB.y);
                xB[k4 * 4 + 2] = swishf(aB.z); xB[k4 * 4 + 3] = swishf(aB.w);
            }
            // ---- layer 2: [16] -> [16] ----
            float yA[kHID], yB[kHID];
            #pragma unroll
            for (int j4 = 0; j4 < 4; ++j4) {
                const float4 bv = ((const float4*)&sB2[h][0])[j4];
                yA[j4 * 4 + 0] = bv.x; yA[j4 * 4 + 1] = bv.y;
                yA[j4 * 4 + 2] = bv.z; yA[j4 * 4 + 3] = bv.w;
                yB[j4 * 4 + 0] = bv.x; yB[j4 * 4 + 1] = bv.y;
                yB[j4 * 4 + 2] = bv.z; yB[j4 * 4 + 3] = bv.w;
            }
            #pragma unroll
            for (int k = 0; k < kHID; ++k) {
                const float xa = xA[k], xb = xB[k];
                #pragma unroll
                for (int j4 = 0; j4 < 4; ++j4) {
                    const float4 w = ((const float4*)&sW2[h][k][0])[j4];
                    yA[j4 * 4 + 0] += xa * w.x; yA[j4 * 4 + 1] += xa * w.y;
                    yA[j4 * 4 + 2] += xa * w.z; yA[j4 * 4 + 3] += xa * w.w;
                    yB[j4 * 4 + 0] += xb * w.x; yB[j4 * 4 + 1] += xb * w.y;
                    yB[j4 * 4 + 2] += xb * w.z; yB[j4 * 4 + 3] += xb * w.w;
                }
            }
            #pragma unroll
            for (int j = 0; j < kHID; ++j) { yA[j] = swishf(yA[j]); yB[j] = swishf(yB[j]); }
            // ---- layer 3: [16] -> 1 ----
            float a3A = sB3[h], a3B = a3A;
            #pragma unroll
            for (int j4 = 0; j4 < 4; ++j4) {
                const float4 w = ((const float4*)&sW3[h][0])[j4];
                a3A += yA[j4 * 4 + 0] * w.x + yA[j4 * 4 + 1] * w.y
                     + yA[j4 * 4 + 2] * w.z + yA[j4 * 4 + 3] * w.w;
                a3B += yB[j4 * 4 + 0] * w.x + yB[j4 * 4 + 1] * w.y
                     + yB[j4 * 4 + 2] * w.z + yB[j4 * 4 + 3] * w.w;
            }
            const float alocA = swishf(a3A);
            const float alocB = swishf(a3B);
            // ---- A_feat: Q[n,h,:] . K[m,h,:] / 16 ----
            float afA = 0.f, afB = 0.f;
            #pragma unroll
            for (int q4 = 0; q4 < kD / 4; ++q4) {
                const float4 qv = ((const float4*)&sQ[h * kD])[q4];  // uniform
                const float4 ka = krA[h * (kD / 4) + q4];
                const float4 kb2 = krB[h * (kD / 4) + q4];
                afA += ka.x * qv.x + ka.y * qv.y + ka.z * qv.z + ka.w * qv.w;
                afB += kb2.x * qv.x + kb2.y * qv.y + kb2.z * qv.z + kb2.w * qv.w;
            }
            sAtt[h][mA] = vA ? (alocA + afA * 0.0625f) : -1e38f;
            sAtt[h][mB] = vB ? (alocB + afB * 0.0625f) : -1e38f;
        }
    }
    __syncthreads();

    // Per-head softmax over m: 32-lane group per head; shuffle masks <32
    // never cross the wave's 32-lane halves.
    {
        const int hg = t >> 5;
        const int lane = t & 31;
        float mx = -3.4e38f;
        #pragma unroll
        for (int j = 0; j < kN / 32; ++j)
            mx = fmaxf(mx, sAtt[hg][lane + 32 * j]);
        #pragma unroll
        for (int off = 16; off; off >>= 1)
            mx = fmaxf(mx, __shfl_xor(mx, off));
        float lsum = 0.f;
        #pragma unroll
        for (int j = 0; j < kN / 32; ++j) {
            const int idx = lane + 32 * j;
            const float e = __expf(sAtt[hg][idx] - mx);  // all-masked row: uniform, matches ref
            sAtt[hg][idx] = e;
            lsum += e;
        }
        #pragma unroll
        for (int off = 16; off; off >>= 1)
            lsum += __shfl_xor(lsum, off);
        if (lane == 0) sInv[hg] = 1.0f / lsum;
    }
    __syncthreads();

    // att @ V: thread (h, d); V reads coalesced (two 128B segs per wave).
    {
        const int h = t >> 5;
        const int dd = t & 31;
        const float* vp = V + (size_t)b * kN * kC + h * kD + dd;
        float a0 = 0.f, a1 = 0.f, a2 = 0.f, a3 = 0.f;
        for (int m = 0; m < kN; m += 4) {
            a0 += sAtt[h][m + 0] * vp[(size_t)(m + 0) * kC];
            a1 += sAtt[h][m + 1] * vp[(size_t)(m + 1) * kC];
            a2 += sAtt[h][m + 2] * vp[(size_t)(m + 2) * kC];
            a3 += sAtt[h][m + 3] * vp[(size_t)(m + 3) * kC];
        }
        out[bn * kC + t] = ((a0 + a1) + (a2 + a3)) * sInv[h];
    }
}

// Final projection: out_pre @ out_w + out_b
__global__ __launch_bounds__(256) void k_proj(
    const float* __restrict__ x,
    const float* __restrict__ w, const float* __restrict__ bias,
    float* __restrict__ y) {
    __shared__ float sx[8][kC];
    const int r0 = blockIdx.x * 8;
    const int t = threadIdx.x;
    #pragma unroll
    for (int r = 0; r < 8; ++r) sx[r][t] = x[(r0 + r) * kC + t];
    __syncthreads();
    float acc[8] = {};
    for (int k = 0; k < kC; ++k) {
        const float wv = w[k * kC + t];
        #pragma unroll
        for (int r = 0; r < 8; ++r) acc[r] += sx[r][k] * wv;
    }
    const float bb = bias[t];
    #pragma unroll
    for (int r = 0; r < 8; ++r) y[(r0 + r) * kC + t] = acc[r] + bb;
}

}  // namespace

extern "C" void kernel_launch(void* const* d_in, const int* in_sizes, int n_in,
                              void* d_out, int out_size, void* d_ws, size_t ws_size,
                              hipStream_t stream) {
    (void)in_sizes; (void)n_in; (void)out_size; (void)ws_size;
    const float* G  = (const float*)d_in[0];
    const float* cf = (const float*)d_in[1];
    const float* wq = (const float*)d_in[2];
    const float* bq = (const float*)d_in[3];
    const float* wk = (const float*)d_in[4];
    const float* bk = (const float*)d_in[5];
    const float* wv = (const float*)d_in[6];   // in_w
    const float* bv = (const float*)d_in[7];   // in_b
    const float* wo = (const float*)d_in[8];   // out_w
    const float* bo = (const float*)d_in[9];   // out_b
    const float* w1 = (const float*)d_in[10];
    const float* b1 = (const float*)d_in[11];
    const float* w2 = (const float*)d_in[12];
    const float* b2 = (const float*)d_in[13];
    const float* w3 = (const float*)d_in[14];
    const float* b3 = (const float*)d_in[15];
    const unsigned char* mraw = (const unsigned char*)d_in[16];

    const int rows = kB * kN;  // 2048
    float* Q = (float*)d_ws;
    float* K = Q + (size_t)rows * kC;
    float* V = K + (size_t)rows * kC;
    float* O = V + (size_t)rows * kC;
    int* mi  = (int*)(O + (size_t)rows * kC);
    // ws usage: 4 * 2 MB + 8 KB

    k_decode_mask<<<1, 256, 0, stream>>>(mraw, mi, rows);
    k_qkv<<<rows / 8, 256, 0, stream>>>(cf, wq, bq, wk, bk, wv, bv, Q, K, V);
    k_attn<<<rows, 256, 0, stream>>>(G, Q, K, V, w1, b1, w2, b2, w3, b3, mi, O);
    k_proj<<<rows / 8, 256, 0, stream>>>(O, wo, bo, (float*)d_out);
}

// Round 3
// 264.321 us; speedup vs baseline: 52.9017x; 1.4084x over previous
//
#include <hip/hip_runtime.h>
#include <math.h>

namespace {

constexpr int kB = 4, kN = 512, kC = 256, kH = 8, kDG = 6, kHID = 16;

typedef _Float16 half2v __attribute__((ext_vector_type(2)));

__device__ __forceinline__ float swishf(float x) {
    return x * __builtin_amdgcn_rcpf(1.0f + __expf(-x));
}

// pack two f32 -> f16x2 (RTN, for staging/weights)
__device__ __forceinline__ unsigned pk16(float a, float b) {
    unsigned short ha = __builtin_bit_cast(unsigned short, (_Float16)a);
    unsigned short hb = __builtin_bit_cast(unsigned short, (_Float16)b);
    return (unsigned)ha | ((unsigned)hb << 16);
}

// pack two f32 -> f16x2 (RTZ single instr, for hot loop)
__device__ __forceinline__ unsigned pkrtz(float a, float b) {
#if __has_builtin(__builtin_amdgcn_cvt_pkrtz)
    return __builtin_bit_cast(unsigned, __builtin_amdgcn_cvt_pkrtz(a, b));
#else
    return pk16(a, b);
#endif
}

// f16x2 dot with f32 accumulate (v_dot2_f32_f16)
__device__ __forceinline__ float fdot2u(unsigned a, unsigned b, float c) {
#if __has_builtin(__builtin_amdgcn_fdot2)
    return __builtin_amdgcn_fdot2(__builtin_bit_cast(half2v, a),
                                  __builtin_bit_cast(half2v, b), c, false);
#else
    half2v ha = __builtin_bit_cast(half2v, a);
    half2v hb = __builtin_bit_cast(half2v, b);
    return c + (float)ha[0] * (float)hb[0] + (float)ha[1] * (float)hb[1];
#endif
}

// QKV projection (blocks 0..511, 4 rows each) + mask decode/compaction
// (block 512). Q,K emitted as packed f16 (RTN); V stays f32.
__global__ __launch_bounds__(256) void k_qkvc(
    const float* __restrict__ x,
    const float* __restrict__ wq, const float* __restrict__ bq,
    const float* __restrict__ wk, const float* __restrict__ bk,
    const float* __restrict__ wv, const float* __restrict__ bv,
    unsigned* __restrict__ Qh, unsigned* __restrict__ Kh,
    float* __restrict__ V,
    const unsigned char* __restrict__ mraw,
    int* __restrict__ list, int* __restrict__ meta) {
    const int t = threadIdx.x;

    if (blockIdx.x == 512) {
        // ---- mask decode (bool-vs-int sniff) + per-b valid-list compaction
        __shared__ int s_isbool;
        if (t == 0) s_isbool = 0;
        __syncthreads();
        int found = 0;
        for (int i = t; i < kB * kN; i += 256)
            if ((i & 3) && mraw[i]) found = 1;  // first 2048 bytes: safe for both layouts
        if (found) atomicOr(&s_isbool, 1);
        __syncthreads();
        const int isb = s_isbool;
        const int b = t >> 6, lane = t & 63;
        const int* mi = (const int*)mraw;
        int base = 0;
        for (int c = 0; c < 8; ++c) {
            const int m = c * 64 + lane;
            const int idx = b * kN + m;
            const int valid = isb ? (mraw[idx] != 0) : (mi[idx] != 0);
            unsigned long long bal = __ballot(valid);
            int rank = (int)__popcll(bal & ((1ull << lane) - 1ull));
            if (valid) list[b * kN + base + rank] = m;
            base += (int)__popcll(bal);
        }
        // tail fill; all-masked fallback = identity list + uniform flag
        for (int i = base + lane; i < kN; i += 64)
            list[b * kN + i] = (base == 0) ? i : 0;
        if (lane == 0) {
            meta[b] = (base == 0) ? kN : base;
            meta[4 + b] = (base == 0);
        }
        return;
    }

    __shared__ float sx[4][kC];
    const int r0 = blockIdx.x * 4;
    #pragma unroll
    for (int r = 0; r < 4; ++r) sx[r][t] = x[(r0 + r) * kC + t];
    __syncthreads();
    float aq[4] = {}, ak[4] = {}, av[4] = {};
    for (int k = 0; k < kC; ++k) {
        const float q = wq[k * kC + t];
        const float kk = wk[k * kC + t];
        const float v = wv[k * kC + t];
        #pragma unroll
        for (int r = 0; r < 4; ++r) {
            aq[r] += sx[r][k] * q;
            ak[r] += sx[r][k] * kk;
            av[r] += sx[r][k] * v;
        }
    }
    const float qb = bq[t], kb = bk[t], vb = bv[t];
    #pragma unroll
    for (int r = 0; r < 4; ++r) {
        const float qv = aq[r] + qb;
        const float kv = ak[r] + kb;
        V[(r0 + r) * kC + t] = av[r] + vb;
        const float qn = __shfl_down(qv, 1);
        const float kn = __shfl_down(kv, 1);
        if ((t & 1) == 0) {
            Qh[(r0 + r) * (kC / 2) + (t >> 1)] = pk16(qv, qn);
            Kh[(r0 + r) * (kC / 2) + (t >> 1)] = pk16(kv, kn);
        }
    }
}

// Fused attention over the COMPACTED valid-m list. One block per (b,n).
__global__ __launch_bounds__(256, 6) void k_attn(
    const float* __restrict__ G,
    const unsigned* __restrict__ Qh,
    const unsigned* __restrict__ Kh,
    const float* __restrict__ V,
    const float* __restrict__ w1, const float* __restrict__ b1,
    const float* __restrict__ w2, const float* __restrict__ b2,
    const float* __restrict__ w3, const float* __restrict__ b3,
    const int* __restrict__ list, const int* __restrict__ meta,
    float* __restrict__ out) {
    __shared__ __align__(16) unsigned sQh[kC / 2];       // 0.5 KB
    __shared__ __align__(16) unsigned sG[kN][4];         // 8 KB (3 g-pairs + pad)
    __shared__ int sList[kN];                            // 2 KB
    __shared__ __align__(16) unsigned sW1[kH][kHID][4];  // 2 KB [h][k][g-pair]
    __shared__ __align__(16) unsigned sW2[kH][kHID][8];  // 4 KB [h][j][k-pair]
    __shared__ float sB1[kH][kHID];
    __shared__ float sB2[kH][kHID];
    __shared__ float sW3[kH][kHID];
    __shared__ float sB3[kH];
    __shared__ float sAtt[kH][kN];                       // 16 KB
    __shared__ float sInv[kH];

    const int bn = blockIdx.x;
    const int b = bn >> 9;
    const int t = threadIdx.x;

    // ---- staging ----
    if (t < kC / 2) sQh[t] = Qh[bn * (kC / 2) + t];
    sList[t] = list[b * kN + t];
    sList[t + 256] = list[b * kN + t + 256];
    #pragma unroll 1
    for (int rep = 0; rep < 2; ++rep) {
        const int m = t + rep * 256;
        const float* gp = G + ((size_t)bn * kN + m) * kDG;
        uint4 gw;
        gw.x = pkrtz(gp[0], gp[1]);
        gw.y = pkrtz(gp[2], gp[3]);
        gw.z = pkrtz(gp[4], gp[5]);
        gw.w = 0;
        *(uint4*)&sG[m][0] = gw;
    }
    if (t < 128) {
        const int h = t >> 4, k = t & 15;
        const float* wp = w1 + (h * kDG) * kHID + k;  // w1[h][g][k], g-stride 16
        sW1[h][k][0] = pk16(wp[0], wp[16]);
        sW1[h][k][1] = pk16(wp[32], wp[48]);
        sW1[h][k][2] = pk16(wp[64], wp[80]);
        sW1[h][k][3] = 0;
        sB1[h][k] = b1[h * kHID + k];
        sB2[h][k] = b2[h * kHID + k];
        sW3[h][k] = w3[h * kHID + k];
    } else {
        const int t2 = t - 128;
        const int h = t2 >> 4, j = t2 & 15;
        const float* wp = w2 + h * kHID * kHID + j;   // w2[h][k][j], k-stride 16
        #pragma unroll
        for (int kp = 0; kp < 8; ++kp)
            sW2[h][j][kp] = pk16(wp[(2 * kp) * kHID], wp[(2 * kp + 1) * kHID]);
        if (j == 0) sB3[h] = b3[h];
    }
    const int nv = meta[b];
    const int allm = meta[4 + b];
    __syncthreads();

    // ---- MLP + QK over compacted pairs (avg nv ~ 256 -> ~1 pair/thread) ----
    #pragma unroll 1
    for (int rep = 0; rep < 2; ++rep) {
        const int mc = t + rep * 256;
        if (mc < nv) {
            const int m = sList[mc];
            const uint4 gw = *(const uint4*)&sG[m][0];
            const unsigned* khrow = Kh + ((size_t)b * kN + m) * (kC / 2);
            #pragma unroll 1
            for (int h = 0; h < kH; ++h) {
                // A_feat: f16 dot, f32 accum
                float af = 0.f;
                const uint4* kh4 = (const uint4*)(khrow + h * 16);
                const uint4* qh4 = (const uint4*)&sQh[h * 16];
                #pragma unroll
                for (int i = 0; i < 4; ++i) {
                    const uint4 kv = kh4[i];
                    const uint4 qv = qh4[i];
                    af = fdot2u(kv.x, qv.x, af);
                    af = fdot2u(kv.y, qv.y, af);
                    af = fdot2u(kv.z, qv.z, af);
                    af = fdot2u(kv.w, qv.w, af);
                }
                // layer 1: [6] -> [16], pack pairs as we go
                unsigned xp[8];
                #pragma unroll
                for (int k2 = 0; k2 < 8; ++k2) {
                    const uint4 wa = *(const uint4*)&sW1[h][2 * k2][0];
                    const uint4 wb = *(const uint4*)&sW1[h][2 * k2 + 1][0];
                    float aa = sB1[h][2 * k2], ab = sB1[h][2 * k2 + 1];
                    aa = fdot2u(gw.x, wa.x, aa);
                    aa = fdot2u(gw.y, wa.y, aa);
                    aa = fdot2u(gw.z, wa.z, aa);
                    ab = fdot2u(gw.x, wb.x, ab);
                    ab = fdot2u(gw.y, wb.y, ab);
                    ab = fdot2u(gw.z, wb.z, ab);
                    xp[k2] = pkrtz(swishf(aa), swishf(ab));
                }
                // layer 2 [16]->[16] + layer 3 [16]->1
                float a3 = sB3[h];
                #pragma unroll
                for (int j = 0; j < kHID; ++j) {
                    const uint4 w0 = ((const uint4*)&sW2[h][j][0])[0];
                    const uint4 w1q = ((const uint4*)&sW2[h][j][0])[1];
                    float acc = sB2[h][j];
                    acc = fdot2u(xp[0], w0.x, acc);
                    acc = fdot2u(xp[1], w0.y, acc);
                    acc = fdot2u(xp[2], w0.z, acc);
                    acc = fdot2u(xp[3], w0.w, acc);
                    acc = fdot2u(xp[4], w1q.x, acc);
                    acc = fdot2u(xp[5], w1q.y, acc);
                    acc = fdot2u(xp[6], w1q.z, acc);
                    acc = fdot2u(xp[7], w1q.w, acc);
                    a3 += swishf(acc) * sW3[h][j];
                }
                sAtt[h][mc] = allm ? 0.f : (swishf(a3) + af * 0.0625f);
            }
        }
    }
    __syncthreads();

    // ---- per-head softmax over compacted range ----
    {
        const int hg = t >> 5;
        const int lane = t & 31;
        const int nv4 = (nv + 3) & ~3;
        float mx = -3.4e38f;
        for (int idx = lane; idx < nv; idx += 32)
            mx = fmaxf(mx, sAtt[hg][idx]);
        #pragma unroll
        for (int off = 16; off; off >>= 1)
            mx = fmaxf(mx, __shfl_xor(mx, off));
        float ls = 0.f;
        for (int idx = lane; idx < nv4; idx += 32) {
            const float e = (idx < nv) ? __expf(sAtt[hg][idx] - mx) : 0.f;
            sAtt[hg][idx] = e;
            ls += e;
        }
        #pragma unroll
        for (int off = 16; off; off >>= 1)
            ls += __shfl_xor(ls, off);
        if (lane == 0) sInv[hg] = 1.0f / ls;
    }
    __syncthreads();

    // ---- att @ V over compacted list (V rows gathered, coalesced in-row) ----
    {
        const int h = t >> 5;
        const int dd = t & 31;
        const int nv4 = (nv + 3) & ~3;
        const float* vb = V + (size_t)b * kN * kC + h * 32 + dd;
        float a0 = 0.f, a1 = 0.f, a2 = 0.f, a3 = 0.f;
        for (int mc = 0; mc < nv4; mc += 4) {
            a0 += sAtt[h][mc + 0] * vb[(size_t)sList[mc + 0] * kC];
            a1 += sAtt[h][mc + 1] * vb[(size_t)sList[mc + 1] * kC];
            a2 += sAtt[h][mc + 2] * vb[(size_t)sList[mc + 2] * kC];
            a3 += sAtt[h][mc + 3] * vb[(size_t)sList[mc + 3] * kC];
        }
        out[bn * kC + t] = ((a0 + a1) + (a2 + a3)) * sInv[h];
    }
}

// Final projection: out_pre @ out_w + out_b
__global__ __launch_bounds__(256) void k_proj(
    const float* __restrict__ x,
    const float* __restrict__ w, const float* __restrict__ bias,
    float* __restrict__ y) {
    __shared__ float sx[8][kC];
    const int r0 = blockIdx.x * 8;
    const int t = threadIdx.x;
    #pragma unroll
    for (int r = 0; r < 8; ++r) sx[r][t] = x[(r0 + r) * kC + t];
    __syncthreads();
    float acc[8] = {};
    for (int k = 0; k < kC; ++k) {
        const float wv = w[k * kC + t];
        #pragma unroll
        for (int r = 0; r < 8; ++r) acc[r] += sx[r][k] * wv;
    }
    const float bb = bias[t];
    #pragma unroll
    for (int r = 0; r < 8; ++r) y[(r0 + r) * kC + t] = acc[r] + bb;
}

}  // namespace

extern "C" void kernel_launch(void* const* d_in, const int* in_sizes, int n_in,
                              void* d_out, int out_size, void* d_ws, size_t ws_size,
                              hipStream_t stream) {
    (void)in_sizes; (void)n_in; (void)out_size; (void)ws_size;
    const float* G  = (const float*)d_in[0];
    const float* cf = (const float*)d_in[1];
    const float* wq = (const float*)d_in[2];
    const float* bq = (const float*)d_in[3];
    const float* wk = (const float*)d_in[4];
    const float* bk = (const float*)d_in[5];
    const float* wv = (const float*)d_in[6];   // in_w
    const float* bv = (const float*)d_in[7];   // in_b
    const float* wo = (const float*)d_in[8];   // out_w
    const float* bo = (const float*)d_in[9];   // out_b
    const float* w1 = (const float*)d_in[10];
    const float* b1 = (const float*)d_in[11];
    const float* w2 = (const float*)d_in[12];
    const float* b2 = (const float*)d_in[13];
    const float* w3 = (const float*)d_in[14];
    const float* b3 = (const float*)d_in[15];
    const unsigned char* mraw = (const unsigned char*)d_in[16];

    const int rows = kB * kN;  // 2048
    unsigned* Qh = (unsigned*)d_ws;                     // 1 MB
    unsigned* Kh = Qh + (size_t)rows * (kC / 2);        // 1 MB
    float* V = (float*)(Kh + (size_t)rows * (kC / 2));  // 2 MB
    float* O = V + (size_t)rows * kC;                   // 2 MB
    int* list = (int*)(O + (size_t)rows * kC);          // 8 KB
    int* meta = list + rows;                            // 32 B

    k_qkvc<<<513, 256, 0, stream>>>(cf, wq, bq, wk, bk, wv, bv,
                                    Qh, Kh, V, mraw, list, meta);
    k_attn<<<rows, 256, 0, stream>>>(G, Qh, Kh, V, w1, b1, w2, b2, w3, b3,
                                     list, meta, O);
    k_proj<<<rows / 8, 256, 0, stream>>>(O, wo, bo, (float*)d_out);
}

// Round 4
// 248.756 us; speedup vs baseline: 56.2119x; 1.0626x over previous
//
#include <hip/hip_runtime.h>
#include <math.h>

namespace {

constexpr int kB = 4, kN = 512, kC = 256, kH = 8, kDG = 6, kHID = 16;

// LDS row strides (uints) chosen so lane-varying-h b128 reads tile 32 banks:
// stride mod 32 must be in {4,12,20,28}; bias arrays use 17 (odd -> distinct banks).
constexpr int S_QH = 20;    // sQh row: 16 data + 4 pad
constexpr int S_W1 = 68;    // 16*4 + 4 pad
constexpr int S_W2 = 132;   // 16*8 + 4 pad
constexpr int S_B  = 17;    // 16 + 1 pad
constexpr int S_AT = 516;   // 512 + 4 pad

typedef _Float16 half2v __attribute__((ext_vector_type(2)));

__device__ __forceinline__ float swishf(float x) {
    return x * __builtin_amdgcn_rcpf(1.0f + __expf(-x));
}

__device__ __forceinline__ unsigned pk16(float a, float b) {
    unsigned short ha = __builtin_bit_cast(unsigned short, (_Float16)a);
    unsigned short hb = __builtin_bit_cast(unsigned short, (_Float16)b);
    return (unsigned)ha | ((unsigned)hb << 16);
}

__device__ __forceinline__ unsigned pkrtz(float a, float b) {
#if __has_builtin(__builtin_amdgcn_cvt_pkrtz)
    return __builtin_bit_cast(unsigned, __builtin_amdgcn_cvt_pkrtz(a, b));
#else
    return pk16(a, b);
#endif
}

__device__ __forceinline__ float fdot2u(unsigned a, unsigned b, float c) {
#if __has_builtin(__builtin_amdgcn_fdot2)
    return __builtin_amdgcn_fdot2(__builtin_bit_cast(half2v, a),
                                  __builtin_bit_cast(half2v, b), c, false);
#else
    half2v ha = __builtin_bit_cast(half2v, a);
    half2v hb = __builtin_bit_cast(half2v, b);
    return c + (float)ha[0] * (float)hb[0] + (float)ha[1] * (float)hb[1];
#endif
}

// QKV projection (blocks 0..511, 4 rows each) + mask decode/compaction
// (block 512). Q,K emitted as packed f16 (RTN); V stays f32.
__global__ __launch_bounds__(256) void k_qkvc(
    const float* __restrict__ x,
    const float* __restrict__ wq, const float* __restrict__ bq,
    const float* __restrict__ wk, const float* __restrict__ bk,
    const float* __restrict__ wv, const float* __restrict__ bv,
    unsigned* __restrict__ Qh, unsigned* __restrict__ Kh,
    float* __restrict__ V,
    const unsigned char* __restrict__ mraw,
    int* __restrict__ list, int* __restrict__ meta) {
    const int t = threadIdx.x;

    if (blockIdx.x == 512) {
        __shared__ int s_isbool;
        if (t == 0) s_isbool = 0;
        __syncthreads();
        int found = 0;
        for (int i = t; i < kB * kN; i += 256)
            if ((i & 3) && mraw[i]) found = 1;
        if (found) atomicOr(&s_isbool, 1);
        __syncthreads();
        const int isb = s_isbool;
        const int b = t >> 6, lane = t & 63;
        const int* mi = (const int*)mraw;
        int base = 0;
        for (int c = 0; c < 8; ++c) {
            const int m = c * 64 + lane;
            const int idx = b * kN + m;
            const int valid = isb ? (mraw[idx] != 0) : (mi[idx] != 0);
            unsigned long long bal = __ballot(valid);
            int rank = (int)__popcll(bal & ((1ull << lane) - 1ull));
            if (valid) list[b * kN + base + rank] = m;
            base += (int)__popcll(bal);
        }
        for (int i = base + lane; i < kN; i += 64)
            list[b * kN + i] = (base == 0) ? i : 0;
        if (lane == 0) {
            meta[b] = (base == 0) ? kN : base;
            meta[4 + b] = (base == 0);
        }
        return;
    }

    __shared__ float sx[4][kC];
    const int r0 = blockIdx.x * 4;
    #pragma unroll
    for (int r = 0; r < 4; ++r) sx[r][t] = x[(r0 + r) * kC + t];
    __syncthreads();
    float aq[4] = {}, ak[4] = {}, av[4] = {};
    for (int k = 0; k < kC; ++k) {
        const float q = wq[k * kC + t];
        const float kk = wk[k * kC + t];
        const float v = wv[k * kC + t];
        #pragma unroll
        for (int r = 0; r < 4; ++r) {
            aq[r] += sx[r][k] * q;
            ak[r] += sx[r][k] * kk;
            av[r] += sx[r][k] * v;
        }
    }
    const float qb = bq[t], kb = bk[t], vb = bv[t];
    #pragma unroll
    for (int r = 0; r < 4; ++r) {
        const float qv = aq[r] + qb;
        const float kv = ak[r] + kb;
        V[(r0 + r) * kC + t] = av[r] + vb;
        const float qn = __shfl_down(qv, 1);
        const float kn = __shfl_down(kv, 1);
        if ((t & 1) == 0) {
            Qh[(r0 + r) * (kC / 2) + (t >> 1)] = pk16(qv, qn);
            Kh[(r0 + r) * (kC / 2) + (t >> 1)] = pk16(kv, kn);
        }
    }
}

// Fused attention over the COMPACTED valid-m list. One block per (b,n).
// Work items are (pair, head): idx -> h = idx&7, mc = idx>>3 -> exact lane
// balance for any nv (round-3's rep-loop ran a full 8-head MLP on nearly
// empty waves whenever nv > 256). All LDS weight arrays are padded so the
// lane-varying-h b128 reads tile the 32 banks (see stride constants).
__global__ __launch_bounds__(256, 4) void k_attn(
    const float* __restrict__ G,
    const unsigned* __restrict__ Qh,
    const unsigned* __restrict__ Kh,
    const float* __restrict__ V,
    const float* __restrict__ w1, const float* __restrict__ b1,
    const float* __restrict__ w2, const float* __restrict__ b2,
    const float* __restrict__ w3, const float* __restrict__ b3,
    const int* __restrict__ list, const int* __restrict__ meta,
    float* __restrict__ out) {
    __shared__ __align__(16) unsigned sQh[kH * S_QH];    // 640 B
    __shared__ __align__(16) uint4 sG4[kN];              // 8 KB
    __shared__ int sList[kN];                            // 2 KB
    __shared__ __align__(16) unsigned sW1[kH * S_W1];    // 2.2 KB
    __shared__ __align__(16) unsigned sW2[kH * S_W2];    // 4.2 KB
    __shared__ float sB1[kH * S_B];
    __shared__ float sB2[kH * S_B];
    __shared__ float sW3[kH * S_B];
    __shared__ float sB3[kH];
    __shared__ float sAtt[kH * S_AT];                    // 16.5 KB
    __shared__ float sInv[kH];

    const int bn = blockIdx.x;
    const int b = bn >> 9;
    const int t = threadIdx.x;

    // ---- staging ----
    if (t < kH * S_QH) {
        const int h = t / S_QH, r = t % S_QH;
        sQh[t] = (r < 16) ? Qh[bn * (kC / 2) + h * 16 + r] : 0u;
    }
    sList[t] = list[b * kN + t];
    sList[t + 256] = list[b * kN + t + 256];
    #pragma unroll 1
    for (int rep = 0; rep < 2; ++rep) {
        const int m = t + rep * 256;
        const float* gp = G + ((size_t)bn * kN + m) * kDG;
        uint4 gw;
        gw.x = pkrtz(gp[0], gp[1]);
        gw.y = pkrtz(gp[2], gp[3]);
        gw.z = pkrtz(gp[4], gp[5]);
        gw.w = 0;
        sG4[m] = gw;
    }
    if (t < 128) {
        const int h = t >> 4, k = t & 15;
        const float* wp = w1 + (h * kDG) * kHID + k;  // w1[h][g][k], g-stride 16
        sW1[h * S_W1 + k * 4 + 0] = pk16(wp[0], wp[16]);
        sW1[h * S_W1 + k * 4 + 1] = pk16(wp[32], wp[48]);
        sW1[h * S_W1 + k * 4 + 2] = pk16(wp[64], wp[80]);
        sW1[h * S_W1 + k * 4 + 3] = 0;
        sB1[h * S_B + k] = b1[h * kHID + k];
        sB2[h * S_B + k] = b2[h * kHID + k];
        sW3[h * S_B + k] = w3[h * kHID + k];
    } else {
        const int t2 = t - 128;
        const int h = t2 >> 4, j = t2 & 15;
        const float* wp = w2 + h * kHID * kHID + j;   // w2[h][k][j], k-stride 16
        #pragma unroll
        for (int kp = 0; kp < 8; ++kp)
            sW2[h * S_W2 + j * 8 + kp] = pk16(wp[(2 * kp) * kHID], wp[(2 * kp + 1) * kHID]);
        if (j == 0) sB3[h] = b3[h];
    }
    const int nv = meta[b];
    const int allm = meta[4 + b];
    __syncthreads();

    // ---- (pair, head) item loop: exact balance ----
    const int items = nv * kH;
    #pragma unroll 1
    for (int base = 0; base < items; base += 256) {
        const int idx = base + t;
        if (idx < items) {
            const int h = idx & 7;
            const int mc = idx >> 3;
            const int m = sList[mc];
            const uint4 gw = sG4[m];
            // A_feat: f16 dot, f32 accum
            const unsigned* khrow = Kh + ((size_t)(b * kN) + m) * (kC / 2) + h * 16;
            float af = 0.f;
            #pragma unroll
            for (int i = 0; i < 4; ++i) {
                const uint4 kv = ((const uint4*)khrow)[i];
                const uint4 qv = *(const uint4*)&sQh[h * S_QH + 4 * i];
                af = fdot2u(kv.x, qv.x, af);
                af = fdot2u(kv.y, qv.y, af);
                af = fdot2u(kv.z, qv.z, af);
                af = fdot2u(kv.w, qv.w, af);
            }
            // layer 1: [6] -> [16]
            unsigned xp[8];
            #pragma unroll
            for (int k2 = 0; k2 < 8; ++k2) {
                const uint4 wa = *(const uint4*)&sW1[h * S_W1 + (2 * k2) * 4];
                const uint4 wb = *(const uint4*)&sW1[h * S_W1 + (2 * k2 + 1) * 4];
                float aa = sB1[h * S_B + 2 * k2], ab = sB1[h * S_B + 2 * k2 + 1];
                aa = fdot2u(gw.x, wa.x, aa);
                aa = fdot2u(gw.y, wa.y, aa);
                aa = fdot2u(gw.z, wa.z, aa);
                ab = fdot2u(gw.x, wb.x, ab);
                ab = fdot2u(gw.y, wb.y, ab);
                ab = fdot2u(gw.z, wb.z, ab);
                xp[k2] = pkrtz(swishf(aa), swishf(ab));
            }
            // layer 2 [16]->[16] + layer 3 [16]->1
            float a3 = sB3[h];
            #pragma unroll
            for (int j = 0; j < kHID; ++j) {
                const uint4 w0 = *(const uint4*)&sW2[h * S_W2 + j * 8];
                const uint4 w1q = *(const uint4*)&sW2[h * S_W2 + j * 8 + 4];
                float acc = sB2[h * S_B + j];
                acc = fdot2u(xp[0], w0.x, acc);
                acc = fdot2u(xp[1], w0.y, acc);
                acc = fdot2u(xp[2], w0.z, acc);
                acc = fdot2u(xp[3], w0.w, acc);
                acc = fdot2u(xp[4], w1q.x, acc);
                acc = fdot2u(xp[5], w1q.y, acc);
                acc = fdot2u(xp[6], w1q.z, acc);
                acc = fdot2u(xp[7], w1q.w, acc);
                a3 += swishf(acc) * sW3[h * S_B + j];
            }
            sAtt[h * S_AT + mc] = allm ? 0.f : (swishf(a3) + af * 0.0625f);
        }
    }
    __syncthreads();

    // ---- per-head softmax over compacted range ----
    {
        const int hg = t >> 5;
        const int lane = t & 31;
        const int nv4 = (nv + 3) & ~3;
        float mx = -3.4e38f;
        for (int idx = lane; idx < nv; idx += 32)
            mx = fmaxf(mx, sAtt[hg * S_AT + idx]);
        #pragma unroll
        for (int off = 16; off; off >>= 1)
            mx = fmaxf(mx, __shfl_xor(mx, off));
        float ls = 0.f;
        for (int idx = lane; idx < nv4; idx += 32) {
            const float e = (idx < nv) ? __expf(sAtt[hg * S_AT + idx] - mx) : 0.f;
            sAtt[hg * S_AT + idx] = e;
            ls += e;
        }
        #pragma unroll
        for (int off = 16; off; off >>= 1)
            ls += __shfl_xor(ls, off);
        if (lane == 0) sInv[hg] = 1.0f / ls;
    }
    __syncthreads();

    // ---- att @ V over compacted list ----
    {
        const int h = t >> 5;
        const int dd = t & 31;
        const int nv4 = (nv + 3) & ~3;
        const float* vb = V + (size_t)b * kN * kC + h * 32 + dd;
        float a0 = 0.f, a1 = 0.f, a2 = 0.f, a3 = 0.f;
        for (int mc = 0; mc < nv4; mc += 4) {
            a0 += sAtt[h * S_AT + mc + 0] * vb[(size_t)sList[mc + 0] * kC];
            a1 += sAtt[h * S_AT + mc + 1] * vb[(size_t)sList[mc + 1] * kC];
            a2 += sAtt[h * S_AT + mc + 2] * vb[(size_t)sList[mc + 2] * kC];
            a3 += sAtt[h * S_AT + mc + 3] * vb[(size_t)sList[mc + 3] * kC];
        }
        out[bn * kC + t] = ((a0 + a1) + (a2 + a3)) * sInv[h];
    }
}

// Final projection: out_pre @ out_w + out_b
__global__ __launch_bounds__(256) void k_proj(
    const float* __restrict__ x,
    const float* __restrict__ w, const float* __restrict__ bias,
    float* __restrict__ y) {
    __shared__ float sx[8][kC];
    const int r0 = blockIdx.x * 8;
    const int t = threadIdx.x;
    #pragma unroll
    for (int r = 0; r < 8; ++r) sx[r][t] = x[(r0 + r) * kC + t];
    __syncthreads();
    float acc[8] = {};
    for (int k = 0; k < kC; ++k) {
        const float wv = w[k * kC + t];
        #pragma unroll
        for (int r = 0; r < 8; ++r) acc[r] += sx[r][k] * wv;
    }
    const float bb = bias[t];
    #pragma unroll
    for (int r = 0; r < 8; ++r) y[(r0 + r) * kC + t] = acc[r] + bb;
}

}  // namespace

extern "C" void kernel_launch(void* const* d_in, const int* in_sizes, int n_in,
                              void* d_out, int out_size, void* d_ws, size_t ws_size,
                              hipStream_t stream) {
    (void)in_sizes; (void)n_in; (void)out_size; (void)ws_size;
    const float* G  = (const float*)d_in[0];
    const float* cf = (const float*)d_in[1];
    const float* wq = (const float*)d_in[2];
    const float* bq = (const float*)d_in[3];
    const float* wk = (const float*)d_in[4];
    const float* bk = (const float*)d_in[5];
    const float* wv = (const float*)d_in[6];   // in_w
    const float* bv = (const float*)d_in[7];   // in_b
    const float* wo = (const float*)d_in[8];   // out_w
    const float* bo = (const float*)d_in[9];   // out_b
    const float* w1 = (const float*)d_in[10];
    const float* b1 = (const float*)d_in[11];
    const float* w2 = (const float*)d_in[12];
    const float* b2 = (const float*)d_in[13];
    const float* w3 = (const float*)d_in[14];
    const float* b3 = (const float*)d_in[15];
    const unsigned char* mraw = (const unsigned char*)d_in[16];

    const int rows = kB * kN;  // 2048
    unsigned* Qh = (unsigned*)d_ws;                     // 1 MB
    unsigned* Kh = Qh + (size_t)rows * (kC / 2);        // 1 MB
    float* V = (float*)(Kh + (size_t)rows * (kC / 2));  // 2 MB
    float* O = V + (size_t)rows * kC;                   // 2 MB
    int* list = (int*)(O + (size_t)rows * kC);          // 8 KB
    int* meta = list + rows;                            // 32 B

    k_qkvc<<<513, 256, 0, stream>>>(cf, wq, bq, wk, bk, wv, bv,
                                    Qh, Kh, V, mraw, list, meta);
    k_attn<<<rows, 256, 0, stream>>>(G, Qh, Kh, V, w1, b1, w2, b2, w3, b3,
                                     list, meta, O);
    k_proj<<<rows / 8, 256, 0, stream>>>(O, wo, bo, (float*)d_out);
}